// Round 16
// baseline (453.857 us; speedup 1.0000x reference)
//
#include <hip/hip_runtime.h>

#define N_POINTS    100000
#define N_KEYPOINTS 16384
#define N_PAIRS     524288
#define D_OUT       300
#define NTILES      19     // ceil(304/16) column tiles for layer 4
#define ONT         19     // out-MLP n tiles (304)
#define OKS         10     // out-MLP k steps (300 -> 320)
#define TP          64     // pairs per LDS tile
#define KPB         4      // keypoints per block

typedef __attribute__((ext_vector_type(8))) short short8;   // 8 bf16 (4 VGPRs)
typedef __attribute__((ext_vector_type(4))) float f32x4;

__device__ inline unsigned short f2bf(float f) {           // RNE fp32 -> bf16
    unsigned u = __builtin_bit_cast(unsigned, f);
    u += 0x7FFFu + ((u >> 16) & 1u);
    return (unsigned short)(u >> 16);
}
__device__ inline float bf2f(unsigned short h) {
    unsigned u = ((unsigned)h) << 16;
    return __builtin_bit_cast(float, u);
}

// ---------------------------------------------------------------------------
// CSR build
// ---------------------------------------------------------------------------
__global__ __launch_bounds__(256) void k_count(const int* __restrict__ si_set,
                                               int* __restrict__ cnt) {
    const int s = blockIdx.x * 256 + threadIdx.x;
    if (s < N_PAIRS) atomicAdd(&cnt[si_set[s]], 1);
}

__global__ __launch_bounds__(256) void k_scan(const int* __restrict__ cnt,
                                              int* __restrict__ off,
                                              int* __restrict__ cursor) {
    __shared__ int part[256];
    const int t = threadIdx.x;
    const int base = t * 64;
    int s = 0;
    for (int k = 0; k < 64; ++k) s += cnt[base + k];
    part[t] = s;
    __syncthreads();
    for (int d = 1; d < 256; d <<= 1) {
        int add = (t >= d) ? part[t - d] : 0;
        __syncthreads();
        part[t] += add;
        __syncthreads();
    }
    int run = part[t] - s;
    for (int k = 0; k < 64; ++k) {
        off[base + k] = run;
        cursor[base + k] = run;
        run += cnt[base + k];
    }
    if (t == 255) off[N_KEYPOINTS] = run;
}

__global__ __launch_bounds__(256) void k_fill(const int* __restrict__ si_set,
                                              int* __restrict__ cursor,
                                              int* __restrict__ pairlist) {
    const int s = blockIdx.x * 256 + threadIdx.x;
    if (s < N_PAIRS) {
        const int st = si_set[s];
        const int pos = atomicAdd(&cursor[st], 1);
        pairlist[pos] = s;
    }
}

// ---------------------------------------------------------------------------
// Weight fragment packers (B-frag order: lane l -> col 16n+(l&15),
// k = 32s + (l>>4)*8 + i), split bf16 hi/lo.
// ---------------------------------------------------------------------------
__global__ __launch_bounds__(256) void k_w4frag(const float* __restrict__ pw4,
                                                unsigned short* __restrict__ fh,
                                                unsigned short* __restrict__ fl) {
    const int tid = blockIdx.x * 256 + threadIdx.x;
    if (tid >= 4 * NTILES * 64) return;
    const int lane = tid & 63;
    const int sn = tid >> 6;
    const int s = sn / NTILES, n = sn % NTILES;
#pragma unroll
    for (int i = 0; i < 8; ++i) {
        const int k = 32 * s + ((lane >> 4) << 3) + i;
        const int col = 16 * n + (lane & 15);
        const float v = (col < D_OUT) ? pw4[k * D_OUT + col] : 0.f;
        const unsigned short h = f2bf(v);
        fh[(size_t)tid * 8 + i] = h;
        fl[(size_t)tid * 8 + i] = f2bf(v - bf2f(h));
    }
}

__global__ __launch_bounds__(256) void k_w3frag(const float* __restrict__ pw3,
                                                unsigned short* __restrict__ fh,
                                                unsigned short* __restrict__ fl) {
    const int tid = blockIdx.x * 256 + threadIdx.x;
    if (tid >= 2 * 8 * 64) return;
    const int lane = tid & 63;
    const int sn = tid >> 6;
    const int s = sn >> 3, n = sn & 7;
#pragma unroll
    for (int i = 0; i < 8; ++i) {
        const int k = 32 * s + ((lane >> 4) << 3) + i;
        const int col = 16 * n + (lane & 15);
        const float v = pw3[k * 128 + col];
        const unsigned short h = f2bf(v);
        fh[(size_t)tid * 8 + i] = h;
        fl[(size_t)tid * 8 + i] = f2bf(v - bf2f(h));
    }
}

__global__ __launch_bounds__(256) void k_w2frag(const float* __restrict__ pw2,
                                                unsigned short* __restrict__ fh,
                                                unsigned short* __restrict__ fl) {
    const int tid = blockIdx.x * 256 + threadIdx.x;
    if (tid >= 4 * 64) return;     // s=0 only, 4 n-tiles
    const int lane = tid & 63;
    const int n = tid >> 6;
#pragma unroll
    for (int i = 0; i < 8; ++i) {
        const int k = ((lane >> 4) << 3) + i;
        const int col = 16 * n + (lane & 15);
        const float v = pw2[k * 64 + col];
        const unsigned short h = f2bf(v);
        fh[(size_t)tid * 8 + i] = h;
        fl[(size_t)tid * 8 + i] = f2bf(v - bf2f(h));
    }
}

// out-MLP weights: 300x300, K padded to 320, N padded to 304
__global__ __launch_bounds__(256) void k_owfrag(const float* __restrict__ src,
                                                unsigned short* __restrict__ fh,
                                                unsigned short* __restrict__ fl) {
    const int tid = blockIdx.x * 256 + threadIdx.x;
    if (tid >= OKS * ONT * 64) return;
    const int lane = tid & 63;
    const int sn = tid >> 6;
    const int s = sn / ONT, n = sn % ONT;
#pragma unroll
    for (int i = 0; i < 8; ++i) {
        const int k = 32 * s + ((lane >> 4) << 3) + i;
        const int col = 16 * n + (lane & 15);
        const float v = (k < D_OUT && col < D_OUT) ? src[k * D_OUT + col] : 0.f;
        const unsigned short h = f2bf(v);
        fh[(size_t)tid * 8 + i] = h;
        fl[(size_t)tid * 8 + i] = f2bf(v - bf2f(h));
    }
}

// ---------------------------------------------------------------------------
// Fused point MLP + segmented max. Block = KPB=4 keypoints, 256 threads.
// Round-15 post-mortem: KPB change null -> not overhead-bound. Audit: Phase B
// re-read a3 once per j-pass (96 of 112 ds_read_b128/wave/tile) -> LDS issue
// stream ~77us is the critical path. Round-16 changes:
//   - Phase B in TWO m-passes (m {0,1},{2,3}): a3 read ONCE per pass
//     (LDS reads 96 -> 32 per wave-tile); all 5 n-tiles per pass with
//     acc[2][5]=40 regs (peak live ~105 < 128). B-frag L2 loads 48 -> 80,
//     each hidden under 6 dependent MFMAs.
//   - s_setprio(1) around MFMA clusters (T5; phase-split structure).
// Everything else frozen from round 15.
// ---------------------------------------------------------------------------
__global__ __launch_bounds__(256, 2) void fused_point(
    const float* __restrict__ features, const float* __restrict__ coords,
    const int* __restrict__ keypoints, const int* __restrict__ set_indices,
    const int* __restrict__ pairlist, const int* __restrict__ off,
    const float* __restrict__ pw1, const float* __restrict__ pb1,
    const short8* __restrict__ w2fh, const short8* __restrict__ w2fl,
    const float* __restrict__ pb2,
    const short8* __restrict__ w3fh, const short8* __restrict__ w3fl,
    const float* __restrict__ pb3,
    const short8* __restrict__ w4fh, const short8* __restrict__ w4fl,
    const float* __restrict__ pb4,
    float* __restrict__ agg)
{
    __shared__ short8 a2h[512],  a2l[512];    // 16 KB x2 A-frags (K=64)
    __shared__ short8 a3h[1024], a3l[1024];   // 32 KB x3 A-frags (K=128)

    unsigned short* const a2hu = (unsigned short*)a2h;
    unsigned short* const a2lu = (unsigned short*)a2l;
    unsigned short* const a3hu = (unsigned short*)a3h;
    unsigned short* const a3lu = (unsigned short*)a3l;

    const int t    = threadIdx.x;
    const int gA   = blockIdx.x * KPB;
    const int lane = t & 63;
    const int w    = __builtin_amdgcn_readfirstlane(t >> 6); // wave 0..3
    const int cc   = lane & 15;
    const int rg   = lane >> 4;

    const int base   = off[gA];
    const int e1     = off[gA + 1];
    const int e2     = off[gA + 2];
    const int e3     = off[gA + 3];
    const int endAll = off[gA + 4];
    const int nt     = (endAll - base + TP - 1) >> 6;

    // hoisted biases
    const int   n0 = w, n1 = w + 4;                 // L3 feat-tiles (both < 8)
    const float b3_0 = pb3[16 * n0 + cc];
    const float b3_1 = pb3[16 * n1 + cc];
    float b2n[4];
#pragma unroll
    for (int n = 0; n < 4; ++n) b2n[n] = pb2[16 * n + cc];

    // per-segment running maxes (all indices compile-time after unroll)
    float vS[KPB][5];
#pragma unroll
    for (int sg = 0; sg < KPB; ++sg)
#pragma unroll
        for (int j = 0; j < 5; ++j) vS[sg][j] = -INFINITY;

    // prefetched gather state
    bool  pvalid = false;
    float x0n[4] = {0.f, 0.f, 0.f, 0.f};

    auto gather = [&](int git) {
        const int t0 = base + (git << 6);
        int np = endAll - t0; if (np > TP) np = TP;
        const int pr = 16 * w + cc;                 // own m-tile pair
        pvalid = (pr < np);
        if (pvalid) {
            const int pair = pairlist[t0 + pr];
            const int pt = set_indices[pair];
            const int st = set_indices[N_PAIRS + pair];
            const int kp = keypoints[st];
            x0n[0] = features[pt];
            x0n[1] = coords[pt * 3 + 0] - coords[kp * 3 + 0];
            x0n[2] = coords[pt * 3 + 1] - coords[kp * 3 + 1];
            x0n[3] = coords[pt * 3 + 2] - coords[kp * 3 + 2];
        }
    };

    // L1 (regs) + L2-MFMA (A = own regs, B = w2f) + scatter into a2
    auto l1l2 = [&](int git) {
        const int t0 = base + (git << 6);
        int np = endAll - t0; if (np > TP) np = TP;
        if (16 * w >= np) return;                   // wave-uniform skip

        short8 ah, al;
        if (pvalid) {
            const int jg = rg << 3;
#pragma unroll
            for (int i = 0; i < 8; ++i) {
                const int j = jg + i;
                float a = pb1[j];
#pragma unroll
                for (int k = 0; k < 4; ++k) a = fmaf(x0n[k], pw1[k * 32 + j], a);
                a = fmaxf(a, 0.f);
                const unsigned u = __builtin_bit_cast(unsigned, a);
                ah[i] = (short)(u >> 16);           // trunc hi
                al[i] = (short)f2bf(a - __builtin_bit_cast(float, u & 0xFFFF0000u));
            }
        } else {
#pragma unroll
            for (int i = 0; i < 8; ++i) { ah[i] = 0; al[i] = 0; }
        }

        f32x4 c[4];
        __builtin_amdgcn_s_setprio(1);
#pragma unroll
        for (int n = 0; n < 4; ++n) {
            c[n] = (f32x4){0.f, 0.f, 0.f, 0.f};
            const short8 bh = w2fh[n * 64 + lane];
            const short8 bl = w2fl[n * 64 + lane];
            c[n] = __builtin_amdgcn_mfma_f32_16x16x32_bf16(ah, bh, c[n], 0, 0, 0);
            c[n] = __builtin_amdgcn_mfma_f32_16x16x32_bf16(al, bh, c[n], 0, 0, 0);
            c[n] = __builtin_amdgcn_mfma_f32_16x16x32_bf16(ah, bl, c[n], 0, 0, 0);
        }
        __builtin_amdgcn_s_setprio(0);
        // scatter: feat f2 = 16n+cc, pair = 16w + 4rg + r
#pragma unroll
        for (int n = 0; n < 4; ++n) {
            const int eb2 = (n >> 1) * 2048 + w * 512 +
                            ((2 * n + (cc >> 3)) & 3) * 128 + (cc & 7) + rg * 32;
#pragma unroll
            for (int r = 0; r < 4; ++r) {
                const float v = fmaxf(c[n][r] + b2n[n], 0.f);
                const unsigned u = __builtin_bit_cast(unsigned, v);
                a2hu[eb2 + r * 8] = (unsigned short)(u >> 16);
                a2lu[eb2 + r * 8] = f2bf(v - __builtin_bit_cast(float, u & 0xFFFF0000u));
            }
        }
    };

    // L3 C-frag -> a3 scatter (verified formula, trunc-hi split)
    auto scatter3 = [&](const f32x4 (&c)[4], int n, float bias, int npc) {
        const int eb = (n >> 1) * 2048 +
                       ((2 * n + (cc >> 3)) & 3) * 128 + (cc & 7) + rg * 32;
#pragma unroll
        for (int m = 0; m < 4; ++m) {
            if (16 * m < npc) {
#pragma unroll
                for (int r = 0; r < 4; ++r) {
                    const float v = fmaxf(c[m][r] + bias, 0.f);
                    const unsigned u = __builtin_bit_cast(unsigned, v);
                    const int e = eb + m * 512 + r * 8;
                    a3hu[e] = (unsigned short)(u >> 16);
                    a3lu[e] = f2bf(v - __builtin_bit_cast(float, u & 0xFFFF0000u));
                }
            }
        }
    };

    // prologue
    if (nt > 0) {
        gather(0);
        l1l2(0);
    }
    __syncthreads();                    // a2 ready

    for (int it = 0; it < nt; ++it) {
        const int t0 = base + (it << 6);
        int npc = endAll - t0; if (npc > TP) npc = TP;
        const bool more = (it + 1) < nt;

        // ---- Phase A: gather prefetch + L3 (a2 -> a3), two n-passes ----
        if (more) gather(it + 1);
#pragma unroll
        for (int pa = 0; pa < 2; ++pa) {
            const int   nn = pa ? n1 : n0;
            const float bb = pa ? b3_1 : b3_0;
            f32x4 c[4];
#pragma unroll
            for (int m = 0; m < 4; ++m) c[m] = (f32x4){0.f, 0.f, 0.f, 0.f};
            __builtin_amdgcn_s_setprio(1);
#pragma unroll
            for (int s = 0; s < 2; ++s) {
                const short8 bh = w3fh[(s * 8 + nn) * 64 + lane];
                const short8 bl = w3fl[(s * 8 + nn) * 64 + lane];
#pragma unroll
                for (int m = 0; m < 4; ++m) {
                    if (16 * m < npc) {
                        const short8 ah = a2h[(s * 4 + m) * 64 + lane];
                        const short8 al = a2l[(s * 4 + m) * 64 + lane];
                        c[m] = __builtin_amdgcn_mfma_f32_16x16x32_bf16(ah, bh, c[m], 0, 0, 0);
                        c[m] = __builtin_amdgcn_mfma_f32_16x16x32_bf16(al, bh, c[m], 0, 0, 0);
                        c[m] = __builtin_amdgcn_mfma_f32_16x16x32_bf16(ah, bl, c[m], 0, 0, 0);
                    }
                }
            }
            __builtin_amdgcn_s_setprio(0);
            scatter3(c, nn, bb, npc);
            __builtin_amdgcn_sched_barrier(0);   // fence load hoisting across passes
        }
        __syncthreads();                // a3 ready; a2 free

        // ---- Phase B: L4 in TWO m-passes; a3 frags read once per pass ----
#pragma unroll
        for (int mp = 0; mp < 2; ++mp) {
            if (32 * mp >= npc) continue;        // block-uniform skip
            f32x4 acc[2][5];
#pragma unroll
            for (int mm = 0; mm < 2; ++mm)
#pragma unroll
                for (int j = 0; j < 5; ++j)
                    acc[mm][j] = (f32x4){0.f, 0.f, 0.f, 0.f};

            __builtin_amdgcn_s_setprio(1);
#pragma unroll
            for (int s = 0; s < 4; ++s) {
                short8 ah[2], al[2];
#pragma unroll
                for (int mm = 0; mm < 2; ++mm) {
                    const int m = mp * 2 + mm;
                    ah[mm] = a3h[(s * 4 + m) * 64 + lane];
                    al[mm] = a3l[(s * 4 + m) * 64 + lane];
                }
#pragma unroll
                for (int j = 0; j < 5; ++j) {
                    const int gn = w + 4 * j;
                    if (gn < NTILES) {
                        const short8 bh = w4fh[(s * NTILES + gn) * 64 + lane];
                        const short8 bl = w4fl[(s * NTILES + gn) * 64 + lane];
#pragma unroll
                        for (int mm = 0; mm < 2; ++mm) {
                            if (16 * (mp * 2 + mm) < npc) {
                                acc[mm][j] = __builtin_amdgcn_mfma_f32_16x16x32_bf16(ah[mm], bh, acc[mm][j], 0, 0, 0);
                                acc[mm][j] = __builtin_amdgcn_mfma_f32_16x16x32_bf16(al[mm], bh, acc[mm][j], 0, 0, 0);
                                acc[mm][j] = __builtin_amdgcn_mfma_f32_16x16x32_bf16(ah[mm], bl, acc[mm][j], 0, 0, 0);
                            }
                        }
                    }
                }
            }
            __builtin_amdgcn_s_setprio(0);

            // seg-max: block-uniform fast path (tile fully in one segment),
            // per-row 4-segment predicated path only for straddling tiles
            const int rb0 = rg << 2;
#pragma unroll
            for (int mm = 0; mm < 2; ++mm) {
                const int m = mp * 2 + mm;
                if (16 * m < npc) {
                    const int g0 = t0 + 16 * m;
                    const int gend = g0 + 16;
                    if (gend <= e1) {
#pragma unroll
                        for (int r = 0; r < 4; ++r)
#pragma unroll
                            for (int j = 0; j < 5; ++j)
                                if (w + 4 * j < NTILES)
                                    vS[0][j] = fmaxf(vS[0][j], acc[mm][j][r]);
                    } else if (g0 >= e1 && gend <= e2) {
#pragma unroll
                        for (int r = 0; r < 4; ++r)
#pragma unroll
                            for (int j = 0; j < 5; ++j)
                                if (w + 4 * j < NTILES)
                                    vS[1][j] = fmaxf(vS[1][j], acc[mm][j][r]);
                    } else if (g0 >= e2 && gend <= e3) {
#pragma unroll
                        for (int r = 0; r < 4; ++r)
#pragma unroll
                            for (int j = 0; j < 5; ++j)
                                if (w + 4 * j < NTILES)
                                    vS[2][j] = fmaxf(vS[2][j], acc[mm][j][r]);
                    } else if (g0 >= e3 && gend <= endAll) {
#pragma unroll
                        for (int r = 0; r < 4; ++r)
#pragma unroll
                            for (int j = 0; j < 5; ++j)
                                if (w + 4 * j < NTILES)
                                    vS[3][j] = fmaxf(vS[3][j], acc[mm][j][r]);
                    } else {                           // straddling tile: per-row
#pragma unroll
                        for (int r = 0; r < 4; ++r) {
                            const int g = g0 + rb0 + r;
                            const bool s0 = (g < e1);
                            const bool s1 = (g >= e1) && (g < e2);
                            const bool s2 = (g >= e2) && (g < e3);
                            const bool s3 = (g >= e3) && (g < endAll);
#pragma unroll
                            for (int j = 0; j < 5; ++j) {
                                if (w + 4 * j < NTILES) {
                                    const float c = acc[mm][j][r];
                                    vS[0][j] = s0 ? fmaxf(vS[0][j], c) : vS[0][j];
                                    vS[1][j] = s1 ? fmaxf(vS[1][j], c) : vS[1][j];
                                    vS[2][j] = s2 ? fmaxf(vS[2][j], c) : vS[2][j];
                                    vS[3][j] = s3 ? fmaxf(vS[3][j], c) : vS[3][j];
                                }
                            }
                        }
                    }
                }
            }
            __builtin_amdgcn_sched_barrier(0);   // fence load hoisting across passes
        }

        if (more) l1l2(it + 1);         // writes a2 (read finished in phase A)
        __syncthreads();                // a2 ready; a3 free
    }

    // column reduce across row-groups; lanes 0-15 hold all cols
#pragma unroll
    for (int sg = 0; sg < KPB; ++sg)
#pragma unroll
        for (int j = 0; j < 5; ++j) {
            vS[sg][j] = fmaxf(vS[sg][j], __shfl_xor(vS[sg][j], 16));
            vS[sg][j] = fmaxf(vS[sg][j], __shfl_xor(vS[sg][j], 32));
        }
    if (lane < 16) {
#pragma unroll
        for (int sg = 0; sg < KPB; ++sg)
#pragma unroll
            for (int j = 0; j < 5; ++j) {
                const int gn = w + 4 * j;
                const int col = 16 * gn + lane;
                if (gn < NTILES && col < D_OUT) {
                    // empty segment: -inf + bias -> relu gives 0
                    agg[(size_t)(gA + sg) * D_OUT + col] =
                        fmaxf(vS[sg][j] + pb4[col], 0.f);
                }
            }
    }
}

// ---------------------------------------------------------------------------
// Output MLP via MFMA (unchanged; in-place safe).
// ---------------------------------------------------------------------------
__global__ __launch_bounds__(320, 2) void k_out(
    const float* __restrict__ agg,
    const short8* __restrict__ o1fh, const short8* __restrict__ o1fl,
    const float* __restrict__ ob1,
    const short8* __restrict__ o2fh, const short8* __restrict__ o2fl,
    const float* __restrict__ ob2,
    float* __restrict__ y)
{
    __shared__ short8 hAh[OKS * 2 * 64];   // 20 KB  slot (s*2+m)*64+lane
    __shared__ short8 hAl[OKS * 2 * 64];   // 20 KB
    unsigned short* const hhu = (unsigned short*)hAh;
    unsigned short* const hlu = (unsigned short*)hAl;

    const int t    = threadIdx.x;
    const int lane = t & 63;
    const int qq   = __builtin_amdgcn_readfirstlane(t >> 6); // 0..4
    const int rb   = blockIdx.x * 32;

    float b1[4], b2[4];
#pragma unroll
    for (int j = 0; j < 4; ++j) {
        const int gn = qq + 5 * j;
        const int col = 16 * gn + (lane & 15);
        b1[j] = (gn < ONT && col < D_OUT) ? ob1[col] : 0.f;
        b2[j] = (gn < ONT && col < D_OUT) ? ob2[col] : 0.f;
    }

    // ---- layer 1: A from global ----
    f32x4 acc[2][4];
#pragma unroll
    for (int m = 0; m < 2; ++m)
#pragma unroll
        for (int j = 0; j < 4; ++j)
            acc[m][j] = (f32x4){0.f, 0.f, 0.f, 0.f};

#pragma unroll
    for (int s = 0; s < OKS; ++s) {
        short8 ah[2], al[2];
#pragma unroll
        for (int m = 0; m < 2; ++m) {
            const int row = rb + (lane & 15) + 16 * m;
            const int kb = 32 * s + ((lane >> 4) << 3);
#pragma unroll
            for (int i = 0; i < 8; ++i) {
                const int k = kb + i;
                const float v = (k < D_OUT) ? agg[(size_t)row * D_OUT + k] : 0.f;
                const unsigned short h = f2bf(v);
                ah[m][i] = (short)h;
                al[m][i] = (short)f2bf(v - bf2f(h));
            }
        }
#pragma unroll
        for (int j = 0; j < 4; ++j) {
            const int gn = qq + 5 * j;
            if (gn < ONT) {
                const short8 bh = o1fh[(s * ONT + gn) * 64 + lane];
                const short8 bl = o1fl[(s * ONT + gn) * 64 + lane];
#pragma unroll
                for (int m = 0; m < 2; ++m) {
                    acc[m][j] = __builtin_amdgcn_mfma_f32_16x16x32_bf16(ah[m], bh, acc[m][j], 0, 0, 0);
                    acc[m][j] = __builtin_amdgcn_mfma_f32_16x16x32_bf16(al[m], bh, acc[m][j], 0, 0, 0);
                    acc[m][j] = __builtin_amdgcn_mfma_f32_16x16x32_bf16(ah[m], bl, acc[m][j], 0, 0, 0);
                }
            }
        }
    }

    // ---- scatter h into LDS A-frag layout ----
#pragma unroll
    for (int j = 0; j < 4; ++j) {
        const int gn = qq + 5 * j;
        if (gn < ONT) {
            const int s2 = (16 * gn + (lane & 15)) >> 5;
            const int kg = ((16 * gn + (lane & 15)) >> 3) & 3;
            const int eb = ((s2 * 2) * 64 + kg * 16 + 4 * (lane >> 4)) * 8 + (lane & 7);
#pragma unroll
            for (int m = 0; m < 2; ++m) {
#pragma unroll
                for (int r = 0; r < 4; ++r) {
                    const float v = fmaxf(acc[m][j][r] + b1[j], 0.f);
                    const unsigned short h = f2bf(v);
                    const int e = eb + m * 512 + r * 8;
                    hhu[e] = h;
                    hlu[e] = f2bf(v - bf2f(h));
                }
            }
        }
    }
    __syncthreads();

    // ---- layer 2: A from LDS ----
    f32x4 acc2[2][4];
#pragma unroll
    for (int m = 0; m < 2; ++m)
#pragma unroll
        for (int j = 0; j < 4; ++j)
            acc2[m][j] = (f32x4){0.f, 0.f, 0.f, 0.f};

#pragma unroll
    for (int s = 0; s < OKS; ++s) {
        short8 ah[2], al[2];
#pragma unroll
        for (int m = 0; m < 2; ++m) {
            ah[m] = hAh[(s * 2 + m) * 64 + lane];
            al[m] = hAl[(s * 2 + m) * 64 + lane];
        }
#pragma unroll
        for (int j = 0; j < 4; ++j) {
            const int gn = qq + 5 * j;
            if (gn < ONT) {
                const short8 bh = o2fh[(s * ONT + gn) * 64 + lane];
                const short8 bl = o2fl[(s * ONT + gn) * 64 + lane];
#pragma unroll
                for (int m = 0; m < 2; ++m) {
                    acc2[m][j] = __builtin_amdgcn_mfma_f32_16x16x32_bf16(ah[m], bh, acc2[m][j], 0, 0, 0);
                    acc2[m][j] = __builtin_amdgcn_mfma_f32_16x16x32_bf16(al[m], bh, acc2[m][j], 0, 0, 0);
                    acc2[m][j] = __builtin_amdgcn_mfma_f32_16x16x32_bf16(ah[m], bl, acc2[m][j], 0, 0, 0);
                }
            }
        }
    }

    // ---- store y ----
    const int rb0 = (lane >> 4) << 2;
#pragma unroll
    for (int m = 0; m < 2; ++m) {
#pragma unroll
        for (int r = 0; r < 4; ++r) {
            const int row = rb + rb0 + r + 16 * m;
#pragma unroll
            for (int j = 0; j < 4; ++j) {
                const int gn = qq + 5 * j;
                const int col = 16 * gn + (lane & 15);
                if (gn < ONT && col < D_OUT)
                    y[(size_t)row * D_OUT + col] = fmaxf(acc2[m][j][r] + b2[j], 0.f);
            }
        }
    }
}

extern "C" void kernel_launch(void* const* d_in, const int* in_sizes, int n_in,
                              void* d_out, int out_size, void* d_ws, size_t ws_size,
                              hipStream_t stream) {
    const float* features    = (const float*)d_in[0];
    const float* coords      = (const float*)d_in[1];
    const int*   keypoints   = (const int*)d_in[2];
    const int*   set_indices = (const int*)d_in[3];
    const float* pw1 = (const float*)d_in[4];
    const float* pb1 = (const float*)d_in[5];
    const float* pw2 = (const float*)d_in[6];
    const float* pb2 = (const float*)d_in[7];
    const float* pw3 = (const float*)d_in[8];
    const float* pb3 = (const float*)d_in[9];
    const float* pw4 = (const float*)d_in[10];
    const float* pb4 = (const float*)d_in[11];
    const float* ow1 = (const float*)d_in[12];
    const float* ob1 = (const float*)d_in[13];
    const float* ow2 = (const float*)d_in[14];
    const float* ob2 = (const float*)d_in[15];

    const int* si_set = set_indices + N_PAIRS;

    // ws layout (~3.3 MB)
    char* w = (char*)d_ws;
    int*            cnt      = (int*)w;             w += 65536;
    int*            off      = (int*)w;             w += 65792;
    int*            cursor   = (int*)w;             w += 65536;
    unsigned short* w4fh     = (unsigned short*)w;  w += 4 * NTILES * 64 * 8 * 2;  // 77824
    unsigned short* w4fl     = (unsigned short*)w;  w += 4 * NTILES * 64 * 8 * 2;
    unsigned short* w3fh     = (unsigned short*)w;  w += 2 * 8 * 64 * 8 * 2;       // 16384
    unsigned short* w3fl     = (unsigned short*)w;  w += 2 * 8 * 64 * 8 * 2;
    unsigned short* w2fh     = (unsigned short*)w;  w += 4 * 64 * 8 * 2;           // 4096
    unsigned short* w2fl     = (unsigned short*)w;  w += 4 * 64 * 8 * 2;
    unsigned short* o1fh     = (unsigned short*)w;  w += OKS * ONT * 64 * 8 * 2;   // 194560
    unsigned short* o1fl     = (unsigned short*)w;  w += OKS * ONT * 64 * 8 * 2;
    unsigned short* o2fh     = (unsigned short*)w;  w += OKS * ONT * 64 * 8 * 2;
    unsigned short* o2fl     = (unsigned short*)w;  w += OKS * ONT * 64 * 8 * 2;
    int*            pairlist = (int*)w;

    float* agg = (float*)d_out;   // k_out runs in-place (per-block row disjoint)
    float* y   = (float*)d_out;

    hipMemsetAsync(cnt, 0, 65536, stream);
    k_w4frag<<<(4 * NTILES * 64 + 255) / 256, 256, 0, stream>>>(pw4, w4fh, w4fl);
    k_w3frag<<<(2 * 8 * 64 + 255) / 256, 256, 0, stream>>>(pw3, w3fh, w3fl);
    k_w2frag<<<1, 256, 0, stream>>>(pw2, w2fh, w2fl);
    k_owfrag<<<(OKS * ONT * 64 + 255) / 256, 256, 0, stream>>>(ow1, o1fh, o1fl);
    k_owfrag<<<(OKS * ONT * 64 + 255) / 256, 256, 0, stream>>>(ow2, o2fh, o2fl);
    k_count<<<N_PAIRS / 256, 256, 0, stream>>>(si_set, cnt);
    k_scan<<<1, 256, 0, stream>>>(cnt, off, cursor);
    k_fill<<<N_PAIRS / 256, 256, 0, stream>>>(si_set, cursor, pairlist);

    fused_point<<<N_KEYPOINTS / KPB, 256, 0, stream>>>(
        features, coords, keypoints, set_indices, pairlist, off,
        pw1, pb1,
        (const short8*)w2fh, (const short8*)w2fl, pb2,
        (const short8*)w3fh, (const short8*)w3fl, pb3,
        (const short8*)w4fh, (const short8*)w4fl, pb4, agg);

    k_out<<<N_KEYPOINTS / 32, 320, 0, stream>>>(
        agg,
        (const short8*)o1fh, (const short8*)o1fl, ob1,
        (const short8*)o2fh, (const short8*)o2fl, ob2, y);
}

// Round 17
// 416.369 us; speedup vs baseline: 1.0900x; 1.0900x over previous
//
#include <hip/hip_runtime.h>

#define N_POINTS    100000
#define N_KEYPOINTS 16384
#define N_PAIRS     524288
#define D_OUT       300
#define NTILES      19     // ceil(304/16) column tiles for layer 4
#define ONT         19     // out-MLP n tiles (304)
#define OKS         10     // out-MLP k steps (300 -> 320)
#define TP          64     // pairs per LDS tile

typedef __attribute__((ext_vector_type(8))) short short8;   // 8 bf16 (4 VGPRs)
typedef __attribute__((ext_vector_type(4))) float f32x4;

__device__ inline unsigned short f2bf(float f) {           // RNE fp32 -> bf16
    unsigned u = __builtin_bit_cast(unsigned, f);
    u += 0x7FFFu + ((u >> 16) & 1u);
    return (unsigned short)(u >> 16);
}
__device__ inline float bf2f(unsigned short h) {
    unsigned u = ((unsigned)h) << 16;
    return __builtin_bit_cast(float, u);
}

// ---------------------------------------------------------------------------
// CSR build
// ---------------------------------------------------------------------------
__global__ __launch_bounds__(256) void k_count(const int* __restrict__ si_set,
                                               int* __restrict__ cnt) {
    const int s = blockIdx.x * 256 + threadIdx.x;
    if (s < N_PAIRS) atomicAdd(&cnt[si_set[s]], 1);
}

__global__ __launch_bounds__(256) void k_scan(const int* __restrict__ cnt,
                                              int* __restrict__ off,
                                              int* __restrict__ cursor) {
    __shared__ int part[256];
    const int t = threadIdx.x;
    const int base = t * 64;
    int s = 0;
    for (int k = 0; k < 64; ++k) s += cnt[base + k];
    part[t] = s;
    __syncthreads();
    for (int d = 1; d < 256; d <<= 1) {
        int add = (t >= d) ? part[t - d] : 0;
        __syncthreads();
        part[t] += add;
        __syncthreads();
    }
    int run = part[t] - s;
    for (int k = 0; k < 64; ++k) {
        off[base + k] = run;
        cursor[base + k] = run;
        run += cnt[base + k];
    }
    if (t == 255) off[N_KEYPOINTS] = run;
}

__global__ __launch_bounds__(256) void k_fill(const int* __restrict__ si_set,
                                              int* __restrict__ cursor,
                                              int* __restrict__ pairlist) {
    const int s = blockIdx.x * 256 + threadIdx.x;
    if (s < N_PAIRS) {
        const int st = si_set[s];
        const int pos = atomicAdd(&cursor[st], 1);
        pairlist[pos] = s;
    }
}

// ---------------------------------------------------------------------------
// Weight fragment packers (B-frag order: lane l -> col 16n+(l&15),
// k = 32s + (l>>4)*8 + i), split bf16 hi/lo.
// ---------------------------------------------------------------------------
__global__ __launch_bounds__(256) void k_w4frag(const float* __restrict__ pw4,
                                                unsigned short* __restrict__ fh,
                                                unsigned short* __restrict__ fl) {
    const int tid = blockIdx.x * 256 + threadIdx.x;
    if (tid >= 4 * NTILES * 64) return;
    const int lane = tid & 63;
    const int sn = tid >> 6;
    const int s = sn / NTILES, n = sn % NTILES;
#pragma unroll
    for (int i = 0; i < 8; ++i) {
        const int k = 32 * s + ((lane >> 4) << 3) + i;
        const int col = 16 * n + (lane & 15);
        const float v = (col < D_OUT) ? pw4[k * D_OUT + col] : 0.f;
        const unsigned short h = f2bf(v);
        fh[(size_t)tid * 8 + i] = h;
        fl[(size_t)tid * 8 + i] = f2bf(v - bf2f(h));
    }
}

__global__ __launch_bounds__(256) void k_w3frag(const float* __restrict__ pw3,
                                                unsigned short* __restrict__ fh,
                                                unsigned short* __restrict__ fl) {
    const int tid = blockIdx.x * 256 + threadIdx.x;
    if (tid >= 2 * 8 * 64) return;
    const int lane = tid & 63;
    const int sn = tid >> 6;
    const int s = sn >> 3, n = sn & 7;
#pragma unroll
    for (int i = 0; i < 8; ++i) {
        const int k = 32 * s + ((lane >> 4) << 3) + i;
        const int col = 16 * n + (lane & 15);
        const float v = pw3[k * 128 + col];
        const unsigned short h = f2bf(v);
        fh[(size_t)tid * 8 + i] = h;
        fl[(size_t)tid * 8 + i] = f2bf(v - bf2f(h));
    }
}

__global__ __launch_bounds__(256) void k_w2frag(const float* __restrict__ pw2,
                                                unsigned short* __restrict__ fh,
                                                unsigned short* __restrict__ fl) {
    const int tid = blockIdx.x * 256 + threadIdx.x;
    if (tid >= 4 * 64) return;     // s=0 only, 4 n-tiles
    const int lane = tid & 63;
    const int n = tid >> 6;
#pragma unroll
    for (int i = 0; i < 8; ++i) {
        const int k = ((lane >> 4) << 3) + i;
        const int col = 16 * n + (lane & 15);
        const float v = pw2[k * 64 + col];
        const unsigned short h = f2bf(v);
        fh[(size_t)tid * 8 + i] = h;
        fl[(size_t)tid * 8 + i] = f2bf(v - bf2f(h));
    }
}

// out-MLP weights: 300x300, K padded to 320, N padded to 304
__global__ __launch_bounds__(256) void k_owfrag(const float* __restrict__ src,
                                                unsigned short* __restrict__ fh,
                                                unsigned short* __restrict__ fl) {
    const int tid = blockIdx.x * 256 + threadIdx.x;
    if (tid >= OKS * ONT * 64) return;
    const int lane = tid & 63;
    const int sn = tid >> 6;
    const int s = sn / ONT, n = sn % ONT;
#pragma unroll
    for (int i = 0; i < 8; ++i) {
        const int k = 32 * s + ((lane >> 4) << 3) + i;
        const int col = 16 * n + (lane & 15);
        const float v = (k < D_OUT && col < D_OUT) ? src[k * D_OUT + col] : 0.f;
        const unsigned short h = f2bf(v);
        fh[(size_t)tid * 8 + i] = h;
        fl[(size_t)tid * 8 + i] = f2bf(v - bf2f(h));
    }
}

// ---------------------------------------------------------------------------
// Fused point MLP + segmented max. Block = 2 keypoints, 256 threads (4 waves).
// Round-16 post-mortem: m-pass restructure + setprio REGRESSED (LDS-read
// volume was not the critical path; setprio hurts lockstep waves). This is
// round 14 (best: 344us) with ONE change: x2 stored as plain RNE bf16
// (a2 hi-only, 8 KB; L3 = 2-term x2*(w3h+w3l)).
//   -> LDS 48 -> 40 KB = 4 blocks/CU (was 3): +33% TLP to hide B-frag L2
//      latency; Phase A MFMA 48->32/wave-tile; a2 scatter halved.
//   -> accuracy: x2 quantization adds ~2^-9 relative on downstream
//      activations; predicted absmax ~1e-3 < 2.5e-3 threshold.
// ---------------------------------------------------------------------------
__global__ __launch_bounds__(256, 2) void fused_point(
    const float* __restrict__ features, const float* __restrict__ coords,
    const int* __restrict__ keypoints, const int* __restrict__ set_indices,
    const int* __restrict__ pairlist, const int* __restrict__ off,
    const float* __restrict__ pw1, const float* __restrict__ pb1,
    const short8* __restrict__ w2fh, const short8* __restrict__ w2fl,
    const float* __restrict__ pb2,
    const short8* __restrict__ w3fh, const short8* __restrict__ w3fl,
    const float* __restrict__ pb3,
    const short8* __restrict__ w4fh, const short8* __restrict__ w4fl,
    const float* __restrict__ pb4,
    float* __restrict__ agg)
{
    __shared__ short8 a2h[512];               //  8 KB x2 A-frags (K=64), RNE bf16
    __shared__ short8 a3h[1024], a3l[1024];   // 32 KB x3 A-frags (K=128), split

    unsigned short* const a2hu = (unsigned short*)a2h;
    unsigned short* const a3hu = (unsigned short*)a3h;
    unsigned short* const a3lu = (unsigned short*)a3l;

    const int t    = threadIdx.x;
    const int gA   = blockIdx.x * 2;
    const int lane = t & 63;
    const int w    = __builtin_amdgcn_readfirstlane(t >> 6); // wave 0..3
    const int cc   = lane & 15;
    const int rg   = lane >> 4;

    const int base   = off[gA];
    const int bnd    = off[gA + 1];
    const int endAll = off[gA + 2];
    const int nt     = (endAll - base + TP - 1) >> 6;

    // hoisted biases
    const int   n0 = w, n1 = w + 4;                 // L3 feat-tiles (both < 8)
    const float b3_0 = pb3[16 * n0 + cc];
    const float b3_1 = pb3[16 * n1 + cc];
    float b2n[4];
#pragma unroll
    for (int n = 0; n < 4; ++n) b2n[n] = pb2[16 * n + cc];

    float vA[5] = {-INFINITY, -INFINITY, -INFINITY, -INFINITY, -INFINITY};
    float vB[5] = {-INFINITY, -INFINITY, -INFINITY, -INFINITY, -INFINITY};

    // prefetched gather state
    bool  pvalid = false;
    float x0n[4] = {0.f, 0.f, 0.f, 0.f};

    auto gather = [&](int git) {
        const int t0 = base + (git << 6);
        int np = endAll - t0; if (np > TP) np = TP;
        const int pr = 16 * w + cc;                 // own m-tile pair
        pvalid = (pr < np);
        if (pvalid) {
            const int pair = pairlist[t0 + pr];
            const int pt = set_indices[pair];
            const int st = set_indices[N_PAIRS + pair];
            const int kp = keypoints[st];
            x0n[0] = features[pt];
            x0n[1] = coords[pt * 3 + 0] - coords[kp * 3 + 0];
            x0n[2] = coords[pt * 3 + 1] - coords[kp * 3 + 1];
            x0n[3] = coords[pt * 3 + 2] - coords[kp * 3 + 2];
        }
    };

    // L1 (regs, split) + L2-MFMA (A = own regs, B = w2f split) -> a2 (RNE bf16)
    auto l1l2 = [&](int git) {
        const int t0 = base + (git << 6);
        int np = endAll - t0; if (np > TP) np = TP;
        if (16 * w >= np) return;                   // wave-uniform skip

        short8 ah, al;
        if (pvalid) {
            const int jg = rg << 3;
#pragma unroll
            for (int i = 0; i < 8; ++i) {
                const int j = jg + i;
                float a = pb1[j];
#pragma unroll
                for (int k = 0; k < 4; ++k) a = fmaf(x0n[k], pw1[k * 32 + j], a);
                a = fmaxf(a, 0.f);
                const unsigned u = __builtin_bit_cast(unsigned, a);
                ah[i] = (short)(u >> 16);           // trunc hi
                al[i] = (short)f2bf(a - __builtin_bit_cast(float, u & 0xFFFF0000u));
            }
        } else {
#pragma unroll
            for (int i = 0; i < 8; ++i) { ah[i] = 0; al[i] = 0; }
        }

        f32x4 c[4];
#pragma unroll
        for (int n = 0; n < 4; ++n) {
            c[n] = (f32x4){0.f, 0.f, 0.f, 0.f};
            const short8 bh = w2fh[n * 64 + lane];
            const short8 bl = w2fl[n * 64 + lane];
            c[n] = __builtin_amdgcn_mfma_f32_16x16x32_bf16(ah, bh, c[n], 0, 0, 0);
            c[n] = __builtin_amdgcn_mfma_f32_16x16x32_bf16(al, bh, c[n], 0, 0, 0);
            c[n] = __builtin_amdgcn_mfma_f32_16x16x32_bf16(ah, bl, c[n], 0, 0, 0);
        }
        // scatter: feat f2 = 16n+cc, pair = 16w + 4rg + r  (RNE bf16, hi only)
#pragma unroll
        for (int n = 0; n < 4; ++n) {
            const int eb2 = (n >> 1) * 2048 + w * 512 +
                            ((2 * n + (cc >> 3)) & 3) * 128 + (cc & 7) + rg * 32;
#pragma unroll
            for (int r = 0; r < 4; ++r) {
                const float v = fmaxf(c[n][r] + b2n[n], 0.f);
                a2hu[eb2 + r * 8] = f2bf(v);
            }
        }
    };

    // L3 C-frag -> a3 scatter (verified formula, trunc-hi split)
    auto scatter3 = [&](const f32x4 (&c)[4], int n, float bias, int npc) {
        const int eb = (n >> 1) * 2048 +
                       ((2 * n + (cc >> 3)) & 3) * 128 + (cc & 7) + rg * 32;
#pragma unroll
        for (int m = 0; m < 4; ++m) {
            if (16 * m < npc) {
#pragma unroll
                for (int r = 0; r < 4; ++r) {
                    const float v = fmaxf(c[m][r] + bias, 0.f);
                    const unsigned u = __builtin_bit_cast(unsigned, v);
                    const int e = eb + m * 512 + r * 8;
                    a3hu[e] = (unsigned short)(u >> 16);
                    a3lu[e] = f2bf(v - __builtin_bit_cast(float, u & 0xFFFF0000u));
                }
            }
        }
    };

    // prologue
    if (nt > 0) {
        gather(0);
        l1l2(0);
    }
    __syncthreads();                    // a2 ready

    for (int it = 0; it < nt; ++it) {
        const int t0 = base + (it << 6);
        int npc = endAll - t0; if (npc > TP) npc = TP;
        const bool more = (it + 1) < nt;

        // ---- Phase A: gather prefetch + L3 (a2 -> a3), two n-passes ----
        // 2-term: x2 (RNE bf16) x (w3h + w3l)
        if (more) gather(it + 1);
#pragma unroll
        for (int pa = 0; pa < 2; ++pa) {
            const int   nn = pa ? n1 : n0;
            const float bb = pa ? b3_1 : b3_0;
            f32x4 c[4];
#pragma unroll
            for (int m = 0; m < 4; ++m) c[m] = (f32x4){0.f, 0.f, 0.f, 0.f};
#pragma unroll
            for (int s = 0; s < 2; ++s) {
                const short8 bh = w3fh[(s * 8 + nn) * 64 + lane];
                const short8 bl = w3fl[(s * 8 + nn) * 64 + lane];
#pragma unroll
                for (int m = 0; m < 4; ++m) {
                    if (16 * m < npc) {
                        const short8 ah = a2h[(s * 4 + m) * 64 + lane];
                        c[m] = __builtin_amdgcn_mfma_f32_16x16x32_bf16(ah, bh, c[m], 0, 0, 0);
                        c[m] = __builtin_amdgcn_mfma_f32_16x16x32_bf16(ah, bl, c[m], 0, 0, 0);
                    }
                }
            }
            scatter3(c, nn, bb, npc);
            __builtin_amdgcn_sched_barrier(0);   // fence load hoisting across passes
        }
        __syncthreads();                // a3 ready; a2 free

        // ---- Phase B: L4 (three j-passes, acc[4][2]) + seg-max, l1l2(it+1) ----
#pragma unroll
        for (int pass = 0; pass < 3; ++pass) {
            const int jbase = 2 * pass;
            if (w + 4 * jbase >= NTILES) continue;   // wave-uniform skip
            f32x4 acc[4][2];
#pragma unroll
            for (int m = 0; m < 4; ++m)
#pragma unroll
                for (int j = 0; j < 2; ++j)
                    acc[m][j] = (f32x4){0.f, 0.f, 0.f, 0.f};

#pragma unroll
            for (int s = 0; s < 4; ++s) {
                short8 ah[4], al[4];
#pragma unroll
                for (int m = 0; m < 4; ++m) {
                    ah[m] = a3h[(s * 4 + m) * 64 + lane];
                    al[m] = a3l[(s * 4 + m) * 64 + lane];
                }
#pragma unroll
                for (int jj = 0; jj < 2; ++jj) {
                    const int gn = w + 4 * (jbase + jj);
                    if (gn < NTILES) {
                        const short8 bh = w4fh[(s * NTILES + gn) * 64 + lane];
                        const short8 bl = w4fl[(s * NTILES + gn) * 64 + lane];
#pragma unroll
                        for (int m = 0; m < 4; ++m) {
                            if (16 * m < npc) {
                                acc[m][jj] = __builtin_amdgcn_mfma_f32_16x16x32_bf16(ah[m], bh, acc[m][jj], 0, 0, 0);
                                acc[m][jj] = __builtin_amdgcn_mfma_f32_16x16x32_bf16(al[m], bh, acc[m][jj], 0, 0, 0);
                                acc[m][jj] = __builtin_amdgcn_mfma_f32_16x16x32_bf16(ah[m], bl, acc[m][jj], 0, 0, 0);
                            }
                        }
                    }
                }
            }

            // seg-max update: block-uniform fast paths for full-A / full-B tiles
            const int rb0 = rg << 2;
#pragma unroll
            for (int m = 0; m < 4; ++m) {
                if (16 * m < npc) {
                    const int g0 = t0 + 16 * m;
                    if (g0 + 16 <= bnd) {                     // whole tile valid, in A
#pragma unroll
                        for (int r = 0; r < 4; ++r)
#pragma unroll
                            for (int jj = 0; jj < 2; ++jj) {
                                const int gn = w + 4 * (jbase + jj);
                                if (gn < NTILES)
                                    vA[jbase + jj] = fmaxf(vA[jbase + jj], acc[m][jj][r]);
                            }
                    } else if (g0 >= bnd && g0 + 16 <= endAll) {  // whole tile valid, in B
#pragma unroll
                        for (int r = 0; r < 4; ++r)
#pragma unroll
                            for (int jj = 0; jj < 2; ++jj) {
                                const int gn = w + 4 * (jbase + jj);
                                if (gn < NTILES)
                                    vB[jbase + jj] = fmaxf(vB[jbase + jj], acc[m][jj][r]);
                            }
                    } else {                                  // boundary tile: per-row
#pragma unroll
                        for (int r = 0; r < 4; ++r) {
                            const int g = g0 + rb0 + r;
                            const bool vld = (g < endAll);
                            const bool inA = (g < bnd);
#pragma unroll
                            for (int jj = 0; jj < 2; ++jj) {
                                const int gn = w + 4 * (jbase + jj);
                                if (gn < NTILES) {
                                    const int j = jbase + jj;
                                    const float c = acc[m][jj][r];
                                    vA[j] = (vld && inA)  ? fmaxf(vA[j], c) : vA[j];
                                    vB[j] = (vld && !inA) ? fmaxf(vB[j], c) : vB[j];
                                }
                            }
                        }
                    }
                }
            }
            __builtin_amdgcn_sched_barrier(0);   // fence load hoisting across passes
        }

        if (more) l1l2(it + 1);         // writes a2 (read finished in phase A)
        __syncthreads();                // a2 ready; a3 free
    }

    // column reduce across row-groups; lanes 0-15 hold all cols
#pragma unroll
    for (int j = 0; j < 5; ++j) {
        vA[j] = fmaxf(vA[j], __shfl_xor(vA[j], 16));
        vA[j] = fmaxf(vA[j], __shfl_xor(vA[j], 32));
        vB[j] = fmaxf(vB[j], __shfl_xor(vB[j], 16));
        vB[j] = fmaxf(vB[j], __shfl_xor(vB[j], 32));
    }
    if (lane < 16) {
#pragma unroll
        for (int j = 0; j < 5; ++j) {
            const int gn = w + 4 * j;
            const int col = 16 * gn + lane;
            if (gn < NTILES && col < D_OUT) {
                // empty segment: -inf + bias -> relu gives 0 (= max(segmax,0))
                agg[(size_t)gA * D_OUT + col]       = fmaxf(vA[j] + pb4[col], 0.f);
                agg[(size_t)(gA + 1) * D_OUT + col] = fmaxf(vB[j] + pb4[col], 0.f);
            }
        }
    }
}

// ---------------------------------------------------------------------------
// Output MLP via MFMA (unchanged; in-place safe).
// ---------------------------------------------------------------------------
__global__ __launch_bounds__(320, 2) void k_out(
    const float* __restrict__ agg,
    const short8* __restrict__ o1fh, const short8* __restrict__ o1fl,
    const float* __restrict__ ob1,
    const short8* __restrict__ o2fh, const short8* __restrict__ o2fl,
    const float* __restrict__ ob2,
    float* __restrict__ y)
{
    __shared__ short8 hAh[OKS * 2 * 64];   // 20 KB  slot (s*2+m)*64+lane
    __shared__ short8 hAl[OKS * 2 * 64];   // 20 KB
    unsigned short* const hhu = (unsigned short*)hAh;
    unsigned short* const hlu = (unsigned short*)hAl;

    const int t    = threadIdx.x;
    const int lane = t & 63;
    const int qq   = __builtin_amdgcn_readfirstlane(t >> 6); // 0..4
    const int rb   = blockIdx.x * 32;

    float b1[4], b2[4];
#pragma unroll
    for (int j = 0; j < 4; ++j) {
        const int gn = qq + 5 * j;
        const int col = 16 * gn + (lane & 15);
        b1[j] = (gn < ONT && col < D_OUT) ? ob1[col] : 0.f;
        b2[j] = (gn < ONT && col < D_OUT) ? ob2[col] : 0.f;
    }

    // ---- layer 1: A from global ----
    f32x4 acc[2][4];
#pragma unroll
    for (int m = 0; m < 2; ++m)
#pragma unroll
        for (int j = 0; j < 4; ++j)
            acc[m][j] = (f32x4){0.f, 0.f, 0.f, 0.f};

#pragma unroll
    for (int s = 0; s < OKS; ++s) {
        short8 ah[2], al[2];
#pragma unroll
        for (int m = 0; m < 2; ++m) {
            const int row = rb + (lane & 15) + 16 * m;
            const int kb = 32 * s + ((lane >> 4) << 3);
#pragma unroll
            for (int i = 0; i < 8; ++i) {
                const int k = kb + i;
                const float v = (k < D_OUT) ? agg[(size_t)row * D_OUT + k] : 0.f;
                const unsigned short h = f2bf(v);
                ah[m][i] = (short)h;
                al[m][i] = (short)f2bf(v - bf2f(h));
            }
        }
#pragma unroll
        for (int j = 0; j < 4; ++j) {
            const int gn = qq + 5 * j;
            if (gn < ONT) {
                const short8 bh = o1fh[(s * ONT + gn) * 64 + lane];
                const short8 bl = o1fl[(s * ONT + gn) * 64 + lane];
#pragma unroll
                for (int m = 0; m < 2; ++m) {
                    acc[m][j] = __builtin_amdgcn_mfma_f32_16x16x32_bf16(ah[m], bh, acc[m][j], 0, 0, 0);
                    acc[m][j] = __builtin_amdgcn_mfma_f32_16x16x32_bf16(al[m], bh, acc[m][j], 0, 0, 0);
                    acc[m][j] = __builtin_amdgcn_mfma_f32_16x16x32_bf16(ah[m], bl, acc[m][j], 0, 0, 0);
                }
            }
        }
    }

    // ---- scatter h into LDS A-frag layout ----
#pragma unroll
    for (int j = 0; j < 4; ++j) {
        const int gn = qq + 5 * j;
        if (gn < ONT) {
            const int s2 = (16 * gn + (lane & 15)) >> 5;
            const int kg = ((16 * gn + (lane & 15)) >> 3) & 3;
            const int eb = ((s2 * 2) * 64 + kg * 16 + 4 * (lane >> 4)) * 8 + (lane & 7);
#pragma unroll
            for (int m = 0; m < 2; ++m) {
#pragma unroll
                for (int r = 0; r < 4; ++r) {
                    const float v = fmaxf(acc[m][j][r] + b1[j], 0.f);
                    const unsigned short h = f2bf(v);
                    const int e = eb + m * 512 + r * 8;
                    hhu[e] = h;
                    hlu[e] = f2bf(v - bf2f(h));
                }
            }
        }
    }
    __syncthreads();

    // ---- layer 2: A from LDS ----
    f32x4 acc2[2][4];
#pragma unroll
    for (int m = 0; m < 2; ++m)
#pragma unroll
        for (int j = 0; j < 4; ++j)
            acc2[m][j] = (f32x4){0.f, 0.f, 0.f, 0.f};

#pragma unroll
    for (int s = 0; s < OKS; ++s) {
        short8 ah[2], al[2];
#pragma unroll
        for (int m = 0; m < 2; ++m) {
            ah[m] = hAh[(s * 2 + m) * 64 + lane];
            al[m] = hAl[(s * 2 + m) * 64 + lane];
        }
#pragma unroll
        for (int j = 0; j < 4; ++j) {
            const int gn = qq + 5 * j;
            if (gn < ONT) {
                const short8 bh = o2fh[(s * ONT + gn) * 64 + lane];
                const short8 bl = o2fl[(s * ONT + gn) * 64 + lane];
#pragma unroll
                for (int m = 0; m < 2; ++m) {
                    acc2[m][j] = __builtin_amdgcn_mfma_f32_16x16x32_bf16(ah[m], bh, acc2[m][j], 0, 0, 0);
                    acc2[m][j] = __builtin_amdgcn_mfma_f32_16x16x32_bf16(al[m], bh, acc2[m][j], 0, 0, 0);
                    acc2[m][j] = __builtin_amdgcn_mfma_f32_16x16x32_bf16(ah[m], bl, acc2[m][j], 0, 0, 0);
                }
            }
        }
    }

    // ---- store y ----
    const int rb0 = (lane >> 4) << 2;
#pragma unroll
    for (int m = 0; m < 2; ++m) {
#pragma unroll
        for (int r = 0; r < 4; ++r) {
            const int row = rb + rb0 + r + 16 * m;
#pragma unroll
            for (int j = 0; j < 4; ++j) {
                const int gn = qq + 5 * j;
                const int col = 16 * gn + (lane & 15);
                if (gn < ONT && col < D_OUT)
                    y[(size_t)row * D_OUT + col] = fmaxf(acc2[m][j][r] + b2[j], 0.f);
            }
        }
    }
}

extern "C" void kernel_launch(void* const* d_in, const int* in_sizes, int n_in,
                              void* d_out, int out_size, void* d_ws, size_t ws_size,
                              hipStream_t stream) {
    const float* features    = (const float*)d_in[0];
    const float* coords      = (const float*)d_in[1];
    const int*   keypoints   = (const int*)d_in[2];
    const int*   set_indices = (const int*)d_in[3];
    const float* pw1 = (const float*)d_in[4];
    const float* pb1 = (const float*)d_in[5];
    const float* pw2 = (const float*)d_in[6];
    const float* pb2 = (const float*)d_in[7];
    const float* pw3 = (const float*)d_in[8];
    const float* pb3 = (const float*)d_in[9];
    const float* pw4 = (const float*)d_in[10];
    const float* pb4 = (const float*)d_in[11];
    const float* ow1 = (const float*)d_in[12];
    const float* ob1 = (const float*)d_in[13];
    const float* ow2 = (const float*)d_in[14];
    const float* ob2 = (const float*)d_in[15];

    const int* si_set = set_indices + N_PAIRS;

    // ws layout (~3.3 MB)
    char* w = (char*)d_ws;
    int*            cnt      = (int*)w;             w += 65536;
    int*            off      = (int*)w;             w += 65792;
    int*            cursor   = (int*)w;             w += 65536;
    unsigned short* w4fh     = (unsigned short*)w;  w += 4 * NTILES * 64 * 8 * 2;  // 77824
    unsigned short* w4fl     = (unsigned short*)w;  w += 4 * NTILES * 64 * 8 * 2;
    unsigned short* w3fh     = (unsigned short*)w;  w += 2 * 8 * 64 * 8 * 2;       // 16384
    unsigned short* w3fl     = (unsigned short*)w;  w += 2 * 8 * 64 * 8 * 2;
    unsigned short* w2fh     = (unsigned short*)w;  w += 4 * 64 * 8 * 2;           // 4096
    unsigned short* w2fl     = (unsigned short*)w;  w += 4 * 64 * 8 * 2;
    unsigned short* o1fh     = (unsigned short*)w;  w += OKS * ONT * 64 * 8 * 2;   // 194560
    unsigned short* o1fl     = (unsigned short*)w;  w += OKS * ONT * 64 * 8 * 2;
    unsigned short* o2fh     = (unsigned short*)w;  w += OKS * ONT * 64 * 8 * 2;
    unsigned short* o2fl     = (unsigned short*)w;  w += OKS * ONT * 64 * 8 * 2;
    int*            pairlist = (int*)w;

    float* agg = (float*)d_out;   // k_out runs in-place (per-block row disjoint)
    float* y   = (float*)d_out;

    hipMemsetAsync(cnt, 0, 65536, stream);
    k_w4frag<<<(4 * NTILES * 64 + 255) / 256, 256, 0, stream>>>(pw4, w4fh, w4fl);
    k_w3frag<<<(2 * 8 * 64 + 255) / 256, 256, 0, stream>>>(pw3, w3fh, w3fl);
    k_w2frag<<<1, 256, 0, stream>>>(pw2, w2fh, w2fl);
    k_owfrag<<<(OKS * ONT * 64 + 255) / 256, 256, 0, stream>>>(ow1, o1fh, o1fl);
    k_owfrag<<<(OKS * ONT * 64 + 255) / 256, 256, 0, stream>>>(ow2, o2fh, o2fl);
    k_count<<<N_PAIRS / 256, 256, 0, stream>>>(si_set, cnt);
    k_scan<<<1, 256, 0, stream>>>(cnt, off, cursor);
    k_fill<<<N_PAIRS / 256, 256, 0, stream>>>(si_set, cursor, pairlist);

    fused_point<<<N_KEYPOINTS / 2, 256, 0, stream>>>(
        features, coords, keypoints, set_indices, pairlist, off,
        pw1, pb1,
        (const short8*)w2fh, (const short8*)w2fl, pb2,
        (const short8*)w3fh, (const short8*)w3fl, pb3,
        (const short8*)w4fh, (const short8*)w4fl, pb4, agg);

    k_out<<<N_KEYPOINTS / 32, 320, 0, stream>>>(
        agg,
        (const short8*)o1fh, (const short8*)o1fl, ob1,
        (const short8*)o2fh, (const short8*)o2fl, ob2, y);
}

// Round 19
// 415.618 us; speedup vs baseline: 1.0920x; 1.0018x over previous
//
#include <hip/hip_runtime.h>

#define N_POINTS    100000
#define N_KEYPOINTS 16384
#define N_PAIRS     524288
#define D_OUT       300
#define NTILES      19     // ceil(304/16) column tiles for layer 4
#define ONT         19     // out-MLP n tiles (304)
#define OKS         10     // out-MLP k steps (300 -> 320)
#define TP          64     // pairs per LDS tile

typedef __attribute__((ext_vector_type(8))) short short8;   // 8 bf16 (4 VGPRs)
typedef __attribute__((ext_vector_type(4))) float f32x4;

__device__ inline unsigned short f2bf(float f) {           // RNE fp32 -> bf16
    unsigned u = __builtin_bit_cast(unsigned, f);
    u += 0x7FFFu + ((u >> 16) & 1u);
    return (unsigned short)(u >> 16);
}
__device__ inline float bf2f(unsigned short h) {
    unsigned u = ((unsigned)h) << 16;
    return __builtin_bit_cast(float, u);
}

// ---------------------------------------------------------------------------
// CSR build
// ---------------------------------------------------------------------------
__global__ __launch_bounds__(256) void k_count(const int* __restrict__ si_set,
                                               int* __restrict__ cnt) {
    const int s = blockIdx.x * 256 + threadIdx.x;
    if (s < N_PAIRS) atomicAdd(&cnt[si_set[s]], 1);
}

__global__ __launch_bounds__(256) void k_scan(const int* __restrict__ cnt,
                                              int* __restrict__ off,
                                              int* __restrict__ cursor) {
    __shared__ int part[256];
    const int t = threadIdx.x;
    const int base = t * 64;
    int s = 0;
    for (int k = 0; k < 64; ++k) s += cnt[base + k];
    part[t] = s;
    __syncthreads();
    for (int d = 1; d < 256; d <<= 1) {
        int add = (t >= d) ? part[t - d] : 0;
        __syncthreads();
        part[t] += add;
        __syncthreads();
    }
    int run = part[t] - s;
    for (int k = 0; k < 64; ++k) {
        off[base + k] = run;
        cursor[base + k] = run;
        run += cnt[base + k];
    }
    if (t == 255) off[N_KEYPOINTS] = run;
}

__global__ __launch_bounds__(256) void k_fill(const int* __restrict__ si_set,
                                              int* __restrict__ cursor,
                                              int* __restrict__ pairlist) {
    const int s = blockIdx.x * 256 + threadIdx.x;
    if (s < N_PAIRS) {
        const int st = si_set[s];
        const int pos = atomicAdd(&cursor[st], 1);
        pairlist[pos] = s;
    }
}

// ---------------------------------------------------------------------------
// Weight fragment packers (B-frag order: lane l -> col 16n+(l&15),
// k = 32s + (l>>4)*8 + i), split bf16 hi/lo.
// ---------------------------------------------------------------------------
__global__ __launch_bounds__(256) void k_w4frag(const float* __restrict__ pw4,
                                                unsigned short* __restrict__ fh,
                                                unsigned short* __restrict__ fl) {
    const int tid = blockIdx.x * 256 + threadIdx.x;
    if (tid >= 4 * NTILES * 64) return;
    const int lane = tid & 63;
    const int sn = tid >> 6;
    const int s = sn / NTILES, n = sn % NTILES;
#pragma unroll
    for (int i = 0; i < 8; ++i) {
        const int k = 32 * s + ((lane >> 4) << 3) + i;
        const int col = 16 * n + (lane & 15);
        const float v = (col < D_OUT) ? pw4[k * D_OUT + col] : 0.f;
        const unsigned short h = f2bf(v);
        fh[(size_t)tid * 8 + i] = h;
        fl[(size_t)tid * 8 + i] = f2bf(v - bf2f(h));
    }
}

__global__ __launch_bounds__(256) void k_w3frag(const float* __restrict__ pw3,
                                                unsigned short* __restrict__ fh,
                                                unsigned short* __restrict__ fl) {
    const int tid = blockIdx.x * 256 + threadIdx.x;
    if (tid >= 2 * 8 * 64) return;
    const int lane = tid & 63;
    const int sn = tid >> 6;
    const int s = sn >> 3, n = sn & 7;
#pragma unroll
    for (int i = 0; i < 8; ++i) {
        const int k = 32 * s + ((lane >> 4) << 3) + i;
        const int col = 16 * n + (lane & 15);
        const float v = pw3[k * 128 + col];
        const unsigned short h = f2bf(v);
        fh[(size_t)tid * 8 + i] = h;
        fl[(size_t)tid * 8 + i] = f2bf(v - bf2f(h));
    }
}

__global__ __launch_bounds__(256) void k_w2frag(const float* __restrict__ pw2,
                                                unsigned short* __restrict__ fh,
                                                unsigned short* __restrict__ fl) {
    const int tid = blockIdx.x * 256 + threadIdx.x;
    if (tid >= 4 * 64) return;     // s=0 only, 4 n-tiles
    const int lane = tid & 63;
    const int n = tid >> 6;
#pragma unroll
    for (int i = 0; i < 8; ++i) {
        const int k = ((lane >> 4) << 3) + i;
        const int col = 16 * n + (lane & 15);
        const float v = pw2[k * 64 + col];
        const unsigned short h = f2bf(v);
        fh[(size_t)tid * 8 + i] = h;
        fl[(size_t)tid * 8 + i] = f2bf(v - bf2f(h));
    }
}

// out-MLP weights: 300x300, K padded to 320, N padded to 304
__global__ __launch_bounds__(256) void k_owfrag(const float* __restrict__ src,
                                                unsigned short* __restrict__ fh,
                                                unsigned short* __restrict__ fl) {
    const int tid = blockIdx.x * 256 + threadIdx.x;
    if (tid >= OKS * ONT * 64) return;
    const int lane = tid & 63;
    const int sn = tid >> 6;
    const int s = sn / ONT, n = sn % ONT;
#pragma unroll
    for (int i = 0; i < 8; ++i) {
        const int k = 32 * s + ((lane >> 4) << 3) + i;
        const int col = 16 * n + (lane & 15);
        const float v = (k < D_OUT && col < D_OUT) ? src[k * D_OUT + col] : 0.f;
        const unsigned short h = f2bf(v);
        fh[(size_t)tid * 8 + i] = h;
        fl[(size_t)tid * 8 + i] = f2bf(v - bf2f(h));
    }
}

// ---------------------------------------------------------------------------
// Fused point MLP + segmented max. Block = 2 keypoints, 256 threads (4 waves).
// REVERT to round-17 exactly (last passing: fused 332us, absmax at floor).
// Round-18's bundled changes (a3 single-bf16 + consolidated prep kernel)
// produced absmax 0.11 -- a packing/semantic bug, cause not isolable from one
// bench. x2 stored as RNE bf16 (a2 hi-only, proven); x3 split hi/lo.
// LDS 40 KB; 2 barriers/tile; sched_barrier fences at pass boundaries.
// ---------------------------------------------------------------------------
__global__ __launch_bounds__(256, 2) void fused_point(
    const float* __restrict__ features, const float* __restrict__ coords,
    const int* __restrict__ keypoints, const int* __restrict__ set_indices,
    const int* __restrict__ pairlist, const int* __restrict__ off,
    const float* __restrict__ pw1, const float* __restrict__ pb1,
    const short8* __restrict__ w2fh, const short8* __restrict__ w2fl,
    const float* __restrict__ pb2,
    const short8* __restrict__ w3fh, const short8* __restrict__ w3fl,
    const float* __restrict__ pb3,
    const short8* __restrict__ w4fh, const short8* __restrict__ w4fl,
    const float* __restrict__ pb4,
    float* __restrict__ agg)
{
    __shared__ short8 a2h[512];               //  8 KB x2 A-frags (K=64), RNE bf16
    __shared__ short8 a3h[1024], a3l[1024];   // 32 KB x3 A-frags (K=128), split

    unsigned short* const a2hu = (unsigned short*)a2h;
    unsigned short* const a3hu = (unsigned short*)a3h;
    unsigned short* const a3lu = (unsigned short*)a3l;

    const int t    = threadIdx.x;
    const int gA   = blockIdx.x * 2;
    const int lane = t & 63;
    const int w    = __builtin_amdgcn_readfirstlane(t >> 6); // wave 0..3
    const int cc   = lane & 15;
    const int rg   = lane >> 4;

    const int base   = off[gA];
    const int bnd    = off[gA + 1];
    const int endAll = off[gA + 2];
    const int nt     = (endAll - base + TP - 1) >> 6;

    // hoisted biases
    const int   n0 = w, n1 = w + 4;                 // L3 feat-tiles (both < 8)
    const float b3_0 = pb3[16 * n0 + cc];
    const float b3_1 = pb3[16 * n1 + cc];
    float b2n[4];
#pragma unroll
    for (int n = 0; n < 4; ++n) b2n[n] = pb2[16 * n + cc];

    float vA[5] = {-INFINITY, -INFINITY, -INFINITY, -INFINITY, -INFINITY};
    float vB[5] = {-INFINITY, -INFINITY, -INFINITY, -INFINITY, -INFINITY};

    // prefetched gather state
    bool  pvalid = false;
    float x0n[4] = {0.f, 0.f, 0.f, 0.f};

    auto gather = [&](int git) {
        const int t0 = base + (git << 6);
        int np = endAll - t0; if (np > TP) np = TP;
        const int pr = 16 * w + cc;                 // own m-tile pair
        pvalid = (pr < np);
        if (pvalid) {
            const int pair = pairlist[t0 + pr];
            const int pt = set_indices[pair];
            const int st = set_indices[N_PAIRS + pair];
            const int kp = keypoints[st];
            x0n[0] = features[pt];
            x0n[1] = coords[pt * 3 + 0] - coords[kp * 3 + 0];
            x0n[2] = coords[pt * 3 + 1] - coords[kp * 3 + 1];
            x0n[3] = coords[pt * 3 + 2] - coords[kp * 3 + 2];
        }
    };

    // L1 (regs, split) + L2-MFMA (A = own regs, B = w2f split) -> a2 (RNE bf16)
    auto l1l2 = [&](int git) {
        const int t0 = base + (git << 6);
        int np = endAll - t0; if (np > TP) np = TP;
        if (16 * w >= np) return;                   // wave-uniform skip

        short8 ah, al;
        if (pvalid) {
            const int jg = rg << 3;
#pragma unroll
            for (int i = 0; i < 8; ++i) {
                const int j = jg + i;
                float a = pb1[j];
#pragma unroll
                for (int k = 0; k < 4; ++k) a = fmaf(x0n[k], pw1[k * 32 + j], a);
                a = fmaxf(a, 0.f);
                const unsigned u = __builtin_bit_cast(unsigned, a);
                ah[i] = (short)(u >> 16);           // trunc hi
                al[i] = (short)f2bf(a - __builtin_bit_cast(float, u & 0xFFFF0000u));
            }
        } else {
#pragma unroll
            for (int i = 0; i < 8; ++i) { ah[i] = 0; al[i] = 0; }
        }

        f32x4 c[4];
#pragma unroll
        for (int n = 0; n < 4; ++n) {
            c[n] = (f32x4){0.f, 0.f, 0.f, 0.f};
            const short8 bh = w2fh[n * 64 + lane];
            const short8 bl = w2fl[n * 64 + lane];
            c[n] = __builtin_amdgcn_mfma_f32_16x16x32_bf16(ah, bh, c[n], 0, 0, 0);
            c[n] = __builtin_amdgcn_mfma_f32_16x16x32_bf16(al, bh, c[n], 0, 0, 0);
            c[n] = __builtin_amdgcn_mfma_f32_16x16x32_bf16(ah, bl, c[n], 0, 0, 0);
        }
        // scatter: feat f2 = 16n+cc, pair = 16w + 4rg + r  (RNE bf16, hi only)
#pragma unroll
        for (int n = 0; n < 4; ++n) {
            const int eb2 = (n >> 1) * 2048 + w * 512 +
                            ((2 * n + (cc >> 3)) & 3) * 128 + (cc & 7) + rg * 32;
#pragma unroll
            for (int r = 0; r < 4; ++r) {
                const float v = fmaxf(c[n][r] + b2n[n], 0.f);
                a2hu[eb2 + r * 8] = f2bf(v);
            }
        }
    };

    // L3 C-frag -> a3 scatter (verified formula, trunc-hi split)
    auto scatter3 = [&](const f32x4 (&c)[4], int n, float bias, int npc) {
        const int eb = (n >> 1) * 2048 +
                       ((2 * n + (cc >> 3)) & 3) * 128 + (cc & 7) + rg * 32;
#pragma unroll
        for (int m = 0; m < 4; ++m) {
            if (16 * m < npc) {
#pragma unroll
                for (int r = 0; r < 4; ++r) {
                    const float v = fmaxf(c[m][r] + bias, 0.f);
                    const unsigned u = __builtin_bit_cast(unsigned, v);
                    const int e = eb + m * 512 + r * 8;
                    a3hu[e] = (unsigned short)(u >> 16);
                    a3lu[e] = f2bf(v - __builtin_bit_cast(float, u & 0xFFFF0000u));
                }
            }
        }
    };

    // prologue
    if (nt > 0) {
        gather(0);
        l1l2(0);
    }
    __syncthreads();                    // a2 ready

    for (int it = 0; it < nt; ++it) {
        const int t0 = base + (it << 6);
        int npc = endAll - t0; if (npc > TP) npc = TP;
        const bool more = (it + 1) < nt;

        // ---- Phase A: gather prefetch + L3 (a2 -> a3), two n-passes ----
        // 2-term: x2 (RNE bf16) x (w3h + w3l)
        if (more) gather(it + 1);
#pragma unroll
        for (int pa = 0; pa < 2; ++pa) {
            const int   nn = pa ? n1 : n0;
            const float bb = pa ? b3_1 : b3_0;
            f32x4 c[4];
#pragma unroll
            for (int m = 0; m < 4; ++m) c[m] = (f32x4){0.f, 0.f, 0.f, 0.f};
#pragma unroll
            for (int s = 0; s < 2; ++s) {
                const short8 bh = w3fh[(s * 8 + nn) * 64 + lane];
                const short8 bl = w3fl[(s * 8 + nn) * 64 + lane];
#pragma unroll
                for (int m = 0; m < 4; ++m) {
                    if (16 * m < npc) {
                        const short8 ah = a2h[(s * 4 + m) * 64 + lane];
                        c[m] = __builtin_amdgcn_mfma_f32_16x16x32_bf16(ah, bh, c[m], 0, 0, 0);
                        c[m] = __builtin_amdgcn_mfma_f32_16x16x32_bf16(ah, bl, c[m], 0, 0, 0);
                    }
                }
            }
            scatter3(c, nn, bb, npc);
            __builtin_amdgcn_sched_barrier(0);   // fence load hoisting across passes
        }
        __syncthreads();                // a3 ready; a2 free

        // ---- Phase B: L4 (three j-passes, acc[4][2]) + seg-max, l1l2(it+1) ----
#pragma unroll
        for (int pass = 0; pass < 3; ++pass) {
            const int jbase = 2 * pass;
            if (w + 4 * jbase >= NTILES) continue;   // wave-uniform skip
            f32x4 acc[4][2];
#pragma unroll
            for (int m = 0; m < 4; ++m)
#pragma unroll
                for (int j = 0; j < 2; ++j)
                    acc[m][j] = (f32x4){0.f, 0.f, 0.f, 0.f};

#pragma unroll
            for (int s = 0; s < 4; ++s) {
                short8 ah[4], al[4];
#pragma unroll
                for (int m = 0; m < 4; ++m) {
                    ah[m] = a3h[(s * 4 + m) * 64 + lane];
                    al[m] = a3l[(s * 4 + m) * 64 + lane];
                }
#pragma unroll
                for (int jj = 0; jj < 2; ++jj) {
                    const int gn = w + 4 * (jbase + jj);
                    if (gn < NTILES) {
                        const short8 bh = w4fh[(s * NTILES + gn) * 64 + lane];
                        const short8 bl = w4fl[(s * NTILES + gn) * 64 + lane];
#pragma unroll
                        for (int m = 0; m < 4; ++m) {
                            if (16 * m < npc) {
                                acc[m][jj] = __builtin_amdgcn_mfma_f32_16x16x32_bf16(ah[m], bh, acc[m][jj], 0, 0, 0);
                                acc[m][jj] = __builtin_amdgcn_mfma_f32_16x16x32_bf16(al[m], bh, acc[m][jj], 0, 0, 0);
                                acc[m][jj] = __builtin_amdgcn_mfma_f32_16x16x32_bf16(ah[m], bl, acc[m][jj], 0, 0, 0);
                            }
                        }
                    }
                }
            }

            // seg-max update: block-uniform fast paths for full-A / full-B tiles
            const int rb0 = rg << 2;
#pragma unroll
            for (int m = 0; m < 4; ++m) {
                if (16 * m < npc) {
                    const int g0 = t0 + 16 * m;
                    if (g0 + 16 <= bnd) {                     // whole tile valid, in A
#pragma unroll
                        for (int r = 0; r < 4; ++r)
#pragma unroll
                            for (int jj = 0; jj < 2; ++jj) {
                                const int gn = w + 4 * (jbase + jj);
                                if (gn < NTILES)
                                    vA[jbase + jj] = fmaxf(vA[jbase + jj], acc[m][jj][r]);
                            }
                    } else if (g0 >= bnd && g0 + 16 <= endAll) {  // whole tile valid, in B
#pragma unroll
                        for (int r = 0; r < 4; ++r)
#pragma unroll
                            for (int jj = 0; jj < 2; ++jj) {
                                const int gn = w + 4 * (jbase + jj);
                                if (gn < NTILES)
                                    vB[jbase + jj] = fmaxf(vB[jbase + jj], acc[m][jj][r]);
                            }
                    } else {                                  // boundary tile: per-row
#pragma unroll
                        for (int r = 0; r < 4; ++r) {
                            const int g = g0 + rb0 + r;
                            const bool vld = (g < endAll);
                            const bool inA = (g < bnd);
#pragma unroll
                            for (int jj = 0; jj < 2; ++jj) {
                                const int gn = w + 4 * (jbase + jj);
                                if (gn < NTILES) {
                                    const int j = jbase + jj;
                                    const float c = acc[m][jj][r];
                                    vA[j] = (vld && inA)  ? fmaxf(vA[j], c) : vA[j];
                                    vB[j] = (vld && !inA) ? fmaxf(vB[j], c) : vB[j];
                                }
                            }
                        }
                    }
                }
            }
            __builtin_amdgcn_sched_barrier(0);   // fence load hoisting across passes
        }

        if (more) l1l2(it + 1);         // writes a2 (read finished in phase A)
        __syncthreads();                // a2 ready; a3 free
    }

    // column reduce across row-groups; lanes 0-15 hold all cols
#pragma unroll
    for (int j = 0; j < 5; ++j) {
        vA[j] = fmaxf(vA[j], __shfl_xor(vA[j], 16));
        vA[j] = fmaxf(vA[j], __shfl_xor(vA[j], 32));
        vB[j] = fmaxf(vB[j], __shfl_xor(vB[j], 16));
        vB[j] = fmaxf(vB[j], __shfl_xor(vB[j], 32));
    }
    if (lane < 16) {
#pragma unroll
        for (int j = 0; j < 5; ++j) {
            const int gn = w + 4 * j;
            const int col = 16 * gn + lane;
            if (gn < NTILES && col < D_OUT) {
                // empty segment: -inf + bias -> relu gives 0 (= max(segmax,0))
                agg[(size_t)gA * D_OUT + col]       = fmaxf(vA[j] + pb4[col], 0.f);
                agg[(size_t)(gA + 1) * D_OUT + col] = fmaxf(vB[j] + pb4[col], 0.f);
            }
        }
    }
}

// ---------------------------------------------------------------------------
// Output MLP via MFMA (unchanged; in-place safe).
// ---------------------------------------------------------------------------
__global__ __launch_bounds__(320, 2) void k_out(
    const float* __restrict__ agg,
    const short8* __restrict__ o1fh, const short8* __restrict__ o1fl,
    const float* __restrict__ ob1,
    const short8* __restrict__ o2fh, const short8* __restrict__ o2fl,
    const float* __restrict__ ob2,
    float* __restrict__ y)
{
    __shared__ short8 hAh[OKS * 2 * 64];   // 20 KB  slot (s*2+m)*64+lane
    __shared__ short8 hAl[OKS * 2 * 64];   // 20 KB
    unsigned short* const hhu = (unsigned short*)hAh;
    unsigned short* const hlu = (unsigned short*)hAl;

    const int t    = threadIdx.x;
    const int lane = t & 63;
    const int qq   = __builtin_amdgcn_readfirstlane(t >> 6); // 0..4
    const int rb   = blockIdx.x * 32;

    float b1[4], b2[4];
#pragma unroll
    for (int j = 0; j < 4; ++j) {
        const int gn = qq + 5 * j;
        const int col = 16 * gn + (lane & 15);
        b1[j] = (gn < ONT && col < D_OUT) ? ob1[col] : 0.f;
        b2[j] = (gn < ONT && col < D_OUT) ? ob2[col] : 0.f;
    }

    // ---- layer 1: A from global ----
    f32x4 acc[2][4];
#pragma unroll
    for (int m = 0; m < 2; ++m)
#pragma unroll
        for (int j = 0; j < 4; ++j)
            acc[m][j] = (f32x4){0.f, 0.f, 0.f, 0.f};

#pragma unroll
    for (int s = 0; s < OKS; ++s) {
        short8 ah[2], al[2];
#pragma unroll
        for (int m = 0; m < 2; ++m) {
            const int row = rb + (lane & 15) + 16 * m;
            const int kb = 32 * s + ((lane >> 4) << 3);
#pragma unroll
            for (int i = 0; i < 8; ++i) {
                const int k = kb + i;
                const float v = (k < D_OUT) ? agg[(size_t)row * D_OUT + k] : 0.f;
                const unsigned short h = f2bf(v);
                ah[m][i] = (short)h;
                al[m][i] = (short)f2bf(v - bf2f(h));
            }
        }
#pragma unroll
        for (int j = 0; j < 4; ++j) {
            const int gn = qq + 5 * j;
            if (gn < ONT) {
                const short8 bh = o1fh[(s * ONT + gn) * 64 + lane];
                const short8 bl = o1fl[(s * ONT + gn) * 64 + lane];
#pragma unroll
                for (int m = 0; m < 2; ++m) {
                    acc[m][j] = __builtin_amdgcn_mfma_f32_16x16x32_bf16(ah[m], bh, acc[m][j], 0, 0, 0);
                    acc[m][j] = __builtin_amdgcn_mfma_f32_16x16x32_bf16(al[m], bh, acc[m][j], 0, 0, 0);
                    acc[m][j] = __builtin_amdgcn_mfma_f32_16x16x32_bf16(ah[m], bl, acc[m][j], 0, 0, 0);
                }
            }
        }
    }

    // ---- scatter h into LDS A-frag layout ----
#pragma unroll
    for (int j = 0; j < 4; ++j) {
        const int gn = qq + 5 * j;
        if (gn < ONT) {
            const int s2 = (16 * gn + (lane & 15)) >> 5;
            const int kg = ((16 * gn + (lane & 15)) >> 3) & 3;
            const int eb = ((s2 * 2) * 64 + kg * 16 + 4 * (lane >> 4)) * 8 + (lane & 7);
#pragma unroll
            for (int m = 0; m < 2; ++m) {
#pragma unroll
                for (int r = 0; r < 4; ++r) {
                    const float v = fmaxf(acc[m][j][r] + b1[j], 0.f);
                    const unsigned short h = f2bf(v);
                    const int e = eb + m * 512 + r * 8;
                    hhu[e] = h;
                    hlu[e] = f2bf(v - bf2f(h));
                }
            }
        }
    }
    __syncthreads();

    // ---- layer 2: A from LDS ----
    f32x4 acc2[2][4];
#pragma unroll
    for (int m = 0; m < 2; ++m)
#pragma unroll
        for (int j = 0; j < 4; ++j)
            acc2[m][j] = (f32x4){0.f, 0.f, 0.f, 0.f};

#pragma unroll
    for (int s = 0; s < OKS; ++s) {
        short8 ah[2], al[2];
#pragma unroll
        for (int m = 0; m < 2; ++m) {
            ah[m] = hAh[(s * 2 + m) * 64 + lane];
            al[m] = hAl[(s * 2 + m) * 64 + lane];
        }
#pragma unroll
        for (int j = 0; j < 4; ++j) {
            const int gn = qq + 5 * j;
            if (gn < ONT) {
                const short8 bh = o2fh[(s * ONT + gn) * 64 + lane];
                const short8 bl = o2fl[(s * ONT + gn) * 64 + lane];
#pragma unroll
                for (int m = 0; m < 2; ++m) {
                    acc2[m][j] = __builtin_amdgcn_mfma_f32_16x16x32_bf16(ah[m], bh, acc2[m][j], 0, 0, 0);
                    acc2[m][j] = __builtin_amdgcn_mfma_f32_16x16x32_bf16(al[m], bh, acc2[m][j], 0, 0, 0);
                    acc2[m][j] = __builtin_amdgcn_mfma_f32_16x16x32_bf16(ah[m], bl, acc2[m][j], 0, 0, 0);
                }
            }
        }
    }

    // ---- store y ----
    const int rb0 = (lane >> 4) << 2;
#pragma unroll
    for (int m = 0; m < 2; ++m) {
#pragma unroll
        for (int r = 0; r < 4; ++r) {
            const int row = rb + rb0 + r + 16 * m;
#pragma unroll
            for (int j = 0; j < 4; ++j) {
                const int gn = qq + 5 * j;
                const int col = 16 * gn + (lane & 15);
                if (gn < ONT && col < D_OUT)
                    y[(size_t)row * D_OUT + col] = fmaxf(acc2[m][j][r] + b2[j], 0.f);
            }
        }
    }
}

extern "C" void kernel_launch(void* const* d_in, const int* in_sizes, int n_in,
                              void* d_out, int out_size, void* d_ws, size_t ws_size,
                              hipStream_t stream) {
    const float* features    = (const float*)d_in[0];
    const float* coords      = (const float*)d_in[1];
    const int*   keypoints   = (const int*)d_in[2];
    const int*   set_indices = (const int*)d_in[3];
    const float* pw1 = (const float*)d_in[4];
    const float* pb1 = (const float*)d_in[5];
    const float* pw2 = (const float*)d_in[6];
    const float* pb2 = (const float*)d_in[7];
    const float* pw3 = (const float*)d_in[8];
    const float* pb3 = (const float*)d_in[9];
    const float* pw4 = (const float*)d_in[10];
    const float* pb4 = (const float*)d_in[11];
    const float* ow1 = (const float*)d_in[12];
    const float* ob1 = (const float*)d_in[13];
    const float* ow2 = (const float*)d_in[14];
    const float* ob2 = (const float*)d_in[15];

    const int* si_set = set_indices + N_PAIRS;

    // ws layout (~3.3 MB)
    char* w = (char*)d_ws;
    int*            cnt      = (int*)w;             w += 65536;
    int*            off      = (int*)w;             w += 65792;
    int*            cursor   = (int*)w;             w += 65536;
    unsigned short* w4fh     = (unsigned short*)w;  w += 4 * NTILES * 64 * 8 * 2;  // 77824
    unsigned short* w4fl     = (unsigned short*)w;  w += 4 * NTILES * 64 * 8 * 2;
    unsigned short* w3fh     = (unsigned short*)w;  w += 2 * 8 * 64 * 8 * 2;       // 16384
    unsigned short* w3fl     = (unsigned short*)w;  w += 2 * 8 * 64 * 8 * 2;
    unsigned short* w2fh     = (unsigned short*)w;  w += 4 * 64 * 8 * 2;           // 4096
    unsigned short* w2fl     = (unsigned short*)w;  w += 4 * 64 * 8 * 2;
    unsigned short* o1fh     = (unsigned short*)w;  w += OKS * ONT * 64 * 8 * 2;   // 194560
    unsigned short* o1fl     = (unsigned short*)w;  w += OKS * ONT * 64 * 8 * 2;
    unsigned short* o2fh     = (unsigned short*)w;  w += OKS * ONT * 64 * 8 * 2;
    unsigned short* o2fl     = (unsigned short*)w;  w += OKS * ONT * 64 * 8 * 2;
    int*            pairlist = (int*)w;

    float* agg = (float*)d_out;   // k_out runs in-place (per-block row disjoint)
    float* y   = (float*)d_out;

    hipMemsetAsync(cnt, 0, 65536, stream);
    k_w4frag<<<(4 * NTILES * 64 + 255) / 256, 256, 0, stream>>>(pw4, w4fh, w4fl);
    k_w3frag<<<(2 * 8 * 64 + 255) / 256, 256, 0, stream>>>(pw3, w3fh, w3fl);
    k_w2frag<<<1, 256, 0, stream>>>(pw2, w2fh, w2fl);
    k_owfrag<<<(OKS * ONT * 64 + 255) / 256, 256, 0, stream>>>(ow1, o1fh, o1fl);
    k_owfrag<<<(OKS * ONT * 64 + 255) / 256, 256, 0, stream>>>(ow2, o2fh, o2fl);
    k_count<<<N_PAIRS / 256, 256, 0, stream>>>(si_set, cnt);
    k_scan<<<1, 256, 0, stream>>>(cnt, off, cursor);
    k_fill<<<N_PAIRS / 256, 256, 0, stream>>>(si_set, cursor, pairlist);

    fused_point<<<N_KEYPOINTS / 2, 256, 0, stream>>>(
        features, coords, keypoints, set_indices, pairlist, off,
        pw1, pb1,
        (const short8*)w2fh, (const short8*)w2fl, pb2,
        (const short8*)w3fh, (const short8*)w3fl, pb3,
        (const short8*)w4fh, (const short8*)w4fl, pb4, agg);

    k_out<<<N_KEYPOINTS / 32, 320, 0, stream>>>(
        agg,
        (const short8*)o1fh, (const short8*)o1fl, ob1,
        (const short8*)o2fh, (const short8*)o2fl, ob2, y);
}